// Round 12
// baseline (208.781 us; speedup 1.0000x reference)
//
#include <hip/hip_runtime.h>

#define WIN      2048
#define HOP      512
#define NFRAMES  16384
#define NBINS    1025      // WIN/2 + 1
#define FPB      8         // frames (= output chunks) per block

__device__ __forceinline__ int pidx(int a) { return a + (a >> 3); }
__device__ __forceinline__ float2 cmul(float2 a, float2 b) {
    return make_float2(a.x * b.x - a.y * b.y, a.x * b.y + a.y * b.x);
}
__device__ __forceinline__ float2 shfl63(float2 v) {    // lane l <-> 63-l
    return make_float2(__shfl_xor(v.x, 63, 64), __shfl_xor(v.y, 63, 64));
}

// ---------------------------------------------------------------------------
// 256 threads, 8 frames, software pipeline, NO spectrum LDS buffer:
// thread->bin map puts Hermitian mirror partners in the same wave at lane^63:
//   lane l<32: b = 32w+l ; l>=32: b = 193-32w+l ; (tid==63 -> b=128)
// so X[1024-k] arrives via __shfl_xor(.,63). Fixed points b=0 (DC, needs
// X[1024]) and b=128 (self-mirror) override from own registers.
// Per frame (4 barriers):
//  P1: convert staged loads -> X (4 bins, k=256m+b); mirrors via shuffle;
//      issue frame fi+1 loads; Hermitian half-size pack (tp = wpb*e^{i pi m/4})
//      fused with radix-4 stage0 (butterfly c=b) -> W1       [barrier]
//  P2-P4: stages s1..s3, tid-based, W1<->W2                  [3 barriers]
//  P5: s4 (twiddle=1) + fftshift + window -> acc0..3 register OLA;
//      flush chunk fi (plain interior / atomic seams); rotate acc.
// LDS = W1+W2 = 18432 B -> 8 blocks/CU (launch_bounds(256,8), grid 2048).
// ---------------------------------------------------------------------------
__global__ __launch_bounds__(256, 8) void istft_kernel(
        const float* __restrict__ mag, const float* __restrict__ ph,
        float* __restrict__ out, int out_size) {
    __shared__ float2 W1[1152];          // 9216 B (pidx-padded 1024)
    __shared__ float2 W2[1152];          // 9216 B

    const int tid    = threadIdx.x;
    const int frame0 = blockIdx.x * FPB;
    const int l  = tid & 63;
    const int wv = tid >> 6;
    int bm = (l < 32) ? (32 * wv + l) : (193 - 32 * wv + l);
    if (tid == 63) bm = 128;             // formula would give 256
    const int b = bm;                    // spectrum base: bins k = 256m + b

    // ---- frame-invariant per-thread constants ----
    float2 wpb;                                    // e^{i pi b/1024}
    sincospif((float)b * (1.0f / 1024.0f), &wpb.y, &wpb.x);
    const float2 w0 = cmul(wpb, wpb);              // stage0 twiddle e^{2pi i b/1024}
    float2 wst[4];                                 // stage twiddles (tid-based)
    wst[0] = w0;                                   // unused slot keeps indices aligned
    sincospif((float)(tid & ~3)  * (1.0f / 512.0f), &wst[1].y, &wst[1].x);
    sincospif((float)(tid & ~15) * (1.0f / 512.0f), &wst[2].y, &wst[2].x);
    sincospif((float)(tid & ~63) * (1.0f / 512.0f), &wst[3].y, &wst[3].x);

    // synthesis window (matches _gl_alg(2048,512,4094) folded with 1/1024)
    float2 rq[4];
    {
        const float inv2047 = 1.0f / 2047.0f;
        const float scale   = rsqrtf(4094.0f);
        float he[4], ho[4];
        float envE = 0.0f, envO = 0.0f;
        #pragma unroll
        for (int w = 0; w < 4; ++w) {
            he[w] = (0.54f - 0.46f * cospif((float)(2 * tid     + 512 * w) * 2.0f * inv2047)) * scale;
            ho[w] = (0.54f - 0.46f * cospif((float)(2 * tid + 1 + 512 * w) * 2.0f * inv2047)) * scale;
            envE += he[w] * he[w];
            envO += ho[w] * ho[w];
        }
        const float se = 1.0f / (envE * 1024.0f);
        const float so = 1.0f / (envO * 1024.0f);
        #pragma unroll
        for (int w = 0; w < 4; ++w) rq[w] = make_float2(he[w] * se, ho[w] * so);
    }
    const float2 r0 = rq[0], r1 = rq[1], r2 = rq[2], r3 = rq[3];
    const float RT = 0.70710678118654752f;         // sqrt(2)/2

    float  mgn[4], ppn[4], nymg, nyph;   // staged loads (current frame at P1)
    float2 acc0, acc1, acc2, acc3;       // live OLA chunks fi..fi+3 @ 2*tid
    acc0 = acc1 = acc2 = acc3 = make_float2(0.0f, 0.0f);

    // ---- prologue: stage frame 0 loads ----
    {
        const float* magf = mag + (size_t)frame0 * NBINS;
        const float* phf  = ph  + (size_t)frame0 * NBINS;
        #pragma unroll
        for (int m = 0; m < 4; ++m) {
            mgn[m] = magf[256 * m + b];
            ppn[m] = phf[256 * m + b];
        }
        nymg = magf[1024]; nyph = phf[1024];
    }

    for (int fi = 0; fi < FPB; ++fi) {
        // ---- P1: convert, shuffle mirrors, issue next loads, pack+s0 ----
        float2 X0, X1, X2, X3, Xn;
        {
            float s, c;
            __sincosf(ppn[0], &s, &c); X0 = make_float2(mgn[0] * c, mgn[0] * s);
            __sincosf(ppn[1], &s, &c); X1 = make_float2(mgn[1] * c, mgn[1] * s);
            __sincosf(ppn[2], &s, &c); X2 = make_float2(mgn[2] * c, mgn[2] * s);
            __sincosf(ppn[3], &s, &c); X3 = make_float2(mgn[3] * c, mgn[3] * s);
            __sincosf(nyph,   &s, &c); Xn = make_float2(nymg * c, 0.0f);
        }
        if (b == 0) X0.y = 0.0f;                   // DC imag dropped
        // mirrors: X[1024-(256m+b)] = partner's X[3-m], partner lane = l^63
        float2 Xm0 = shfl63(X3), Xm1 = shfl63(X2), Xm2 = shfl63(X1), Xm3 = shfl63(X0);
        if (b == 0)   { Xm0 = Xn; Xm1 = X3; Xm2 = X2; Xm3 = X1; }   // tid 0
        if (b == 128) { Xm0 = X3; Xm1 = X2; Xm2 = X1; Xm3 = X0; }   // tid 63

        if (fi < FPB - 1) {                        // issue next-frame loads
            const float* magf = mag + (size_t)(frame0 + fi + 1) * NBINS;
            const float* phf  = ph  + (size_t)(frame0 + fi + 1) * NBINS;
            #pragma unroll
            for (int m = 0; m < 4; ++m) {
                mgn[m] = magf[256 * m + b];
                ppn[m] = phf[256 * m + b];
            }
            nymg = magf[1024]; nyph = phf[1024];
        }

        // pack Zf[256m+b] = E + O', tp = wpb * e^{i pi m/4}; then stage0 (c=b)
        {
            float2 z[4];
            #pragma unroll
            for (int m = 0; m < 4; ++m) {
                float2 Xk = (m == 0) ? X0 : (m == 1) ? X1 : (m == 2) ? X2 : X3;
                float2 Xm = (m == 0) ? Xm0 : (m == 1) ? Xm1 : (m == 2) ? Xm2 : Xm3;
                float2 tp;
                if      (m == 0) tp = wpb;
                else if (m == 1) tp = make_float2(RT * (wpb.x - wpb.y), RT * (wpb.x + wpb.y));
                else if (m == 2) tp = make_float2(-wpb.y, wpb.x);
                else             tp = make_float2(-RT * (wpb.x + wpb.y), RT * (wpb.x - wpb.y));
                float Er = 0.5f * (Xk.x + Xm.x), Ei = 0.5f * (Xk.y - Xm.y);
                float Tr = Xm.x - Xk.x,          Ti = -(Xm.y + Xk.y);
                float Or = 0.5f * (tp.x * Ti + tp.y * Tr);
                float Oi = 0.5f * (tp.y * Ti - tp.x * Tr);
                z[m] = make_float2(Er + Or, Ei + Oi);
            }
            const float2 w = w0, w2 = cmul(w0, w0);
            float2 u0 = make_float2(z[0].x + z[2].x, z[0].y + z[2].y);
            float  ar = z[0].x - z[2].x, ai = z[0].y - z[2].y;
            float2 u1 = make_float2(ar * w.x - ai * w.y, ar * w.y + ai * w.x);
            float2 u2 = make_float2(z[1].x + z[3].x, z[1].y + z[3].y);
            float  br = z[1].x - z[3].x, bi = z[1].y - z[3].y;
            float2 u3 = make_float2(-br * w.y - bi * w.x, br * w.x - bi * w.y);
            const int base = 4 * b;                // butterfly c=b, s4=1
            W1[pidx(base)]     = make_float2(u0.x + u2.x, u0.y + u2.y);
            W1[pidx(base + 1)] = make_float2(u1.x + u3.x, u1.y + u3.y);
            float dr = u0.x - u2.x, di = u0.y - u2.y;
            W1[pidx(base + 2)] = make_float2(dr * w2.x - di * w2.y, dr * w2.y + di * w2.x);
            float er = u1.x - u3.x, ei = u1.y - u3.y;
            W1[pidx(base + 3)] = make_float2(er * w2.x - ei * w2.y, er * w2.y + ei * w2.x);
        }
        __syncthreads();

        // ---- P2/P3/P4: stages 1..3 (tid-based) ----
        #pragma unroll
        for (int st = 1; st < 4; ++st) {
            float2* src = (st == 2) ? W2 : W1;     // s1:W1->W2 s2:W2->W1 s3:W1->W2
            float2* dst = (st == 2) ? W1 : W2;
            const int s4 = 1 << (2 * st);
            const int G  = tid & ~(s4 - 1);
            const float2 w = wst[st];
            const float2 w2 = cmul(w, w);
            float2 x0 = src[pidx(tid)];
            float2 x1 = src[pidx(tid + 256)];
            float2 x2 = src[pidx(tid + 512)];
            float2 x3 = src[pidx(tid + 768)];
            float2 u0 = make_float2(x0.x + x2.x, x0.y + x2.y);
            float  ar = x0.x - x2.x, ai = x0.y - x2.y;
            float2 u1 = make_float2(ar * w.x - ai * w.y, ar * w.y + ai * w.x);
            float2 u2 = make_float2(x1.x + x3.x, x1.y + x3.y);
            float  br = x1.x - x3.x, bi = x1.y - x3.y;
            float2 u3 = make_float2(-br * w.y - bi * w.x, br * w.x - bi * w.y);
            const int base = tid + 3 * G;
            dst[pidx(base)]          = make_float2(u0.x + u2.x, u0.y + u2.y);
            dst[pidx(base + s4)]     = make_float2(u1.x + u3.x, u1.y + u3.y);
            float dr = u0.x - u2.x, di = u0.y - u2.y;
            dst[pidx(base + 2 * s4)] = make_float2(dr * w2.x - di * w2.y, dr * w2.y + di * w2.x);
            float er = u1.x - u3.x, ei = u1.y - u3.y;
            dst[pidx(base + 3 * s4)] = make_float2(er * w2.x - ei * w2.y, er * w2.y + ei * w2.x);
            __syncthreads();
        }
        // data now in W2

        // ---- P5: s4 (w=1) + fftshift + window -> register OLA; flush ----
        {
            float2 x0 = W2[pidx(tid)];
            float2 x1 = W2[pidx(tid + 256)];
            float2 x2 = W2[pidx(tid + 512)];
            float2 x3 = W2[pidx(tid + 768)];
            float2 u0 = make_float2(x0.x + x2.x, x0.y + x2.y);
            float2 u1 = make_float2(x0.x - x2.x, x0.y - x2.y);
            float2 u2 = make_float2(x1.x + x3.x, x1.y + x3.y);
            float2 u3 = make_float2(-(x1.y - x3.y), x1.x - x3.x);   // i*(x1-x3)
            float2 y;
            // n=tid+512 -> t2=tid     -> chunk fi   (acc0), window r0
            y = make_float2(u0.x - u2.x, u0.y - u2.y);
            acc0.x += y.x * r0.x;  acc0.y += y.y * r0.y;
            // n=tid+768 -> t2=tid+256 -> chunk fi+1 (acc1), window r1
            y = make_float2(u1.x - u3.x, u1.y - u3.y);
            acc1.x += y.x * r1.x;  acc1.y += y.y * r1.y;
            // n=tid     -> t2=tid+512 -> chunk fi+2 (acc2), window r2
            y = make_float2(u0.x + u2.x, u0.y + u2.y);
            acc2.x += y.x * r2.x;  acc2.y += y.y * r2.y;
            // n=tid+256 -> t2=tid+768 -> chunk fi+3 (acc3), window r3
            y = make_float2(u1.x + u3.x, u1.y + u3.y);
            acc3.x += y.x * r3.x;  acc3.y += y.y * r3.y;

            // flush chunk fi (complete)
            float2 v = acc0;
            long p = (long)(frame0 + fi) * HOP + 2 * tid - 1536;
            if (fi >= 3) {                           // interior: plain store
                if (p >= 0 && p < out_size)         out[p]     = v.x;
                if (p + 1 >= 0 && p + 1 < out_size) out[p + 1] = v.y;
            } else {                                 // seam: atomic
                if (p >= 0 && p < out_size)         atomicAdd(out + p,     v.x);
                if (p + 1 >= 0 && p + 1 < out_size) atomicAdd(out + p + 1, v.y);
            }
            // rotate accumulators
            acc0 = acc1; acc1 = acc2; acc2 = acc3;
            acc3 = make_float2(0.0f, 0.0f);
        }
        // no barrier: next write to W-buffers is behind P1's barrier
    }

    // ---- tail: chunks FPB..FPB+2 partial -> atomic ----
    #pragma unroll
    for (int e = 0; e < 3; ++e) {
        float2 v = (e == 0) ? acc0 : (e == 1) ? acc1 : acc2;
        long p = (long)(frame0 + FPB + e) * HOP + 2 * tid - 1536;
        if (p >= 0 && p < out_size)         atomicAdd(out + p,     v.x);
        if (p + 1 >= 0 && p + 1 < out_size) atomicAdd(out + p + 1, v.y);
    }
}

extern "C" void kernel_launch(void* const* d_in, const int* in_sizes, int n_in,
                              void* d_out, int out_size, void* d_ws, size_t ws_size,
                              hipStream_t stream) {
    const float* mag = (const float*)d_in[0];
    const float* ph  = (const float*)d_in[1];
    float* out = (float*)d_out;

    hipMemsetAsync(d_out, 0, (size_t)out_size * sizeof(float), stream);
    istft_kernel<<<NFRAMES / FPB, 256, 0, stream>>>(mag, ph, out, out_size);
}

// Round 13
// 180.872 us; speedup vs baseline: 1.1543x; 1.1543x over previous
//
#include <hip/hip_runtime.h>

#define WIN      2048
#define HOP      512
#define NFRAMES  16384
#define NBINS    1025      // WIN/2 + 1
#define FPB      8         // frames (= output chunks) per block

__device__ __forceinline__ int pidx(int a) { return a + (a >> 3); }
__device__ __forceinline__ float2 cmul(float2 a, float2 b) {
    return make_float2(a.x * b.x - a.y * b.y, a.x * b.y + a.y * b.x);
}
__device__ __forceinline__ float2 shfl63(float2 v) {    // lane l <-> 63-l
    return make_float2(__shfl_xor(v.x, 63, 64), __shfl_xor(v.y, 63, 64));
}

// ---------------------------------------------------------------------------
// 256 threads, 8 frames, software pipeline, NO spectrum LDS buffer:
// thread->bin map puts Hermitian mirror partners in the same wave at lane^63:
//   lane l<32: b = 32w+l ; l>=32: b = 193-32w+l ; (tid==63 -> b=128)
// so X[1024-k] arrives via __shfl_xor(.,63). Fixed points b=0 (DC, needs
// X[1024]) and b=128 (self-mirror) override from own registers.
// Per frame (4 barriers):
//  P1: convert staged loads -> X (4 bins, k=256m+b); mirrors via shuffle;
//      issue frame fi+1 loads; Hermitian half-size pack (tp = wpb*e^{i pi m/4})
//      fused with radix-4 stage0 (butterfly c=b) -> W1       [barrier]
//  P2-P4: stages s1..s3, tid-based, W1<->W2                  [3 barriers]
//  P5: s4 (twiddle=1) + fftshift + window -> acc0..3 register OLA;
//      flush chunk fi (plain interior / atomic seams); rotate acc.
// LDS = W1+W2 = 18432 B. launch_bounds(256,6): VGPR cap 85 (R11's bigger body
// compiled to 64 -> no spill expected; R12's (256,8)=64-cap spilled, 503 MB
// scratch fetch). 6 blocks/CU.
// ---------------------------------------------------------------------------
__global__ __launch_bounds__(256, 6) void istft_kernel(
        const float* __restrict__ mag, const float* __restrict__ ph,
        float* __restrict__ out, int out_size) {
    __shared__ float2 W1[1152];          // 9216 B (pidx-padded 1024)
    __shared__ float2 W2[1152];          // 9216 B

    const int tid    = threadIdx.x;
    const int frame0 = blockIdx.x * FPB;
    const int l  = tid & 63;
    const int wv = tid >> 6;
    int bm = (l < 32) ? (32 * wv + l) : (193 - 32 * wv + l);
    if (tid == 63) bm = 128;             // formula would give 256
    const int b = bm;                    // spectrum base: bins k = 256m + b

    // ---- frame-invariant per-thread constants ----
    float2 wpb;                                    // e^{i pi b/1024}
    sincospif((float)b * (1.0f / 1024.0f), &wpb.y, &wpb.x);
    const float2 w0 = cmul(wpb, wpb);              // stage0 twiddle e^{2pi i b/1024}
    float2 wst1, wst2, wst3;                       // stage twiddles (tid-based)
    sincospif((float)(tid & ~3)  * (1.0f / 512.0f), &wst1.y, &wst1.x);
    sincospif((float)(tid & ~15) * (1.0f / 512.0f), &wst2.y, &wst2.x);
    sincospif((float)(tid & ~63) * (1.0f / 512.0f), &wst3.y, &wst3.x);

    // synthesis window (matches _gl_alg(2048,512,4094) folded with 1/1024)
    float2 rq[4];
    {
        const float inv2047 = 1.0f / 2047.0f;
        const float scale   = rsqrtf(4094.0f);
        float he[4], ho[4];
        float envE = 0.0f, envO = 0.0f;
        #pragma unroll
        for (int w = 0; w < 4; ++w) {
            he[w] = (0.54f - 0.46f * cospif((float)(2 * tid     + 512 * w) * 2.0f * inv2047)) * scale;
            ho[w] = (0.54f - 0.46f * cospif((float)(2 * tid + 1 + 512 * w) * 2.0f * inv2047)) * scale;
            envE += he[w] * he[w];
            envO += ho[w] * ho[w];
        }
        const float se = 1.0f / (envE * 1024.0f);
        const float so = 1.0f / (envO * 1024.0f);
        #pragma unroll
        for (int w = 0; w < 4; ++w) rq[w] = make_float2(he[w] * se, ho[w] * so);
    }
    const float2 r0 = rq[0], r1 = rq[1], r2 = rq[2], r3 = rq[3];
    const float RT = 0.70710678118654752f;         // sqrt(2)/2

    float  mgn[4], ppn[4], nymg, nyph;   // staged loads (current frame at P1)
    float2 acc0, acc1, acc2, acc3;       // live OLA chunks fi..fi+3 @ 2*tid
    acc0 = acc1 = acc2 = acc3 = make_float2(0.0f, 0.0f);

    // ---- prologue: stage frame 0 loads ----
    {
        const float* magf = mag + (size_t)frame0 * NBINS;
        const float* phf  = ph  + (size_t)frame0 * NBINS;
        #pragma unroll
        for (int m = 0; m < 4; ++m) {
            mgn[m] = magf[256 * m + b];
            ppn[m] = phf[256 * m + b];
        }
        nymg = magf[1024]; nyph = phf[1024];
    }

    for (int fi = 0; fi < FPB; ++fi) {
        // ---- P1: convert, shuffle mirrors, issue next loads, pack+s0 ----
        float2 X0, X1, X2, X3, Xn;
        {
            float s, c;
            __sincosf(ppn[0], &s, &c); X0 = make_float2(mgn[0] * c, mgn[0] * s);
            __sincosf(ppn[1], &s, &c); X1 = make_float2(mgn[1] * c, mgn[1] * s);
            __sincosf(ppn[2], &s, &c); X2 = make_float2(mgn[2] * c, mgn[2] * s);
            __sincosf(ppn[3], &s, &c); X3 = make_float2(mgn[3] * c, mgn[3] * s);
            __sincosf(nyph,   &s, &c); Xn = make_float2(nymg * c, 0.0f);
        }
        if (b == 0) X0.y = 0.0f;                   // DC imag dropped
        // mirrors: X[1024-(256m+b)] = partner's X[3-m], partner lane = l^63
        float2 Xm0 = shfl63(X3), Xm1 = shfl63(X2), Xm2 = shfl63(X1), Xm3 = shfl63(X0);
        if (b == 0)   { Xm0 = Xn; Xm1 = X3; Xm2 = X2; Xm3 = X1; }   // tid 0
        if (b == 128) { Xm0 = X3; Xm1 = X2; Xm2 = X1; Xm3 = X0; }   // tid 63

        if (fi < FPB - 1) {                        // issue next-frame loads
            const float* magf = mag + (size_t)(frame0 + fi + 1) * NBINS;
            const float* phf  = ph  + (size_t)(frame0 + fi + 1) * NBINS;
            #pragma unroll
            for (int m = 0; m < 4; ++m) {
                mgn[m] = magf[256 * m + b];
                ppn[m] = phf[256 * m + b];
            }
            nymg = magf[1024]; nyph = phf[1024];
        }

        // pack Zf[256m+b] = E + O', tp = wpb * e^{i pi m/4}; then stage0 (c=b)
        {
            float2 z[4];
            #pragma unroll
            for (int m = 0; m < 4; ++m) {
                float2 Xk = (m == 0) ? X0 : (m == 1) ? X1 : (m == 2) ? X2 : X3;
                float2 Xm = (m == 0) ? Xm0 : (m == 1) ? Xm1 : (m == 2) ? Xm2 : Xm3;
                float2 tp;
                if      (m == 0) tp = wpb;
                else if (m == 1) tp = make_float2(RT * (wpb.x - wpb.y), RT * (wpb.x + wpb.y));
                else if (m == 2) tp = make_float2(-wpb.y, wpb.x);
                else             tp = make_float2(-RT * (wpb.x + wpb.y), RT * (wpb.x - wpb.y));
                float Er = 0.5f * (Xk.x + Xm.x), Ei = 0.5f * (Xk.y - Xm.y);
                float Tr = Xm.x - Xk.x,          Ti = -(Xm.y + Xk.y);
                float Or = 0.5f * (tp.x * Ti + tp.y * Tr);
                float Oi = 0.5f * (tp.y * Ti - tp.x * Tr);
                z[m] = make_float2(Er + Or, Ei + Oi);
            }
            const float2 w = w0, w2 = cmul(w0, w0);
            float2 u0 = make_float2(z[0].x + z[2].x, z[0].y + z[2].y);
            float  ar = z[0].x - z[2].x, ai = z[0].y - z[2].y;
            float2 u1 = make_float2(ar * w.x - ai * w.y, ar * w.y + ai * w.x);
            float2 u2 = make_float2(z[1].x + z[3].x, z[1].y + z[3].y);
            float  br = z[1].x - z[3].x, bi = z[1].y - z[3].y;
            float2 u3 = make_float2(-br * w.y - bi * w.x, br * w.x - bi * w.y);
            const int base = 4 * b;                // butterfly c=b, s4=1
            W1[pidx(base)]     = make_float2(u0.x + u2.x, u0.y + u2.y);
            W1[pidx(base + 1)] = make_float2(u1.x + u3.x, u1.y + u3.y);
            float dr = u0.x - u2.x, di = u0.y - u2.y;
            W1[pidx(base + 2)] = make_float2(dr * w2.x - di * w2.y, dr * w2.y + di * w2.x);
            float er = u1.x - u3.x, ei = u1.y - u3.y;
            W1[pidx(base + 3)] = make_float2(er * w2.x - ei * w2.y, er * w2.y + ei * w2.x);
        }
        __syncthreads();

        // ---- P2/P3/P4: stages 1..3 (tid-based) ----
        #pragma unroll
        for (int st = 1; st < 4; ++st) {
            float2* src = (st == 2) ? W2 : W1;     // s1:W1->W2 s2:W2->W1 s3:W1->W2
            float2* dst = (st == 2) ? W1 : W2;
            const int s4 = 1 << (2 * st);
            const int G  = tid & ~(s4 - 1);
            const float2 w = (st == 1) ? wst1 : (st == 2) ? wst2 : wst3;
            const float2 w2 = cmul(w, w);
            float2 x0 = src[pidx(tid)];
            float2 x1 = src[pidx(tid + 256)];
            float2 x2 = src[pidx(tid + 512)];
            float2 x3 = src[pidx(tid + 768)];
            float2 u0 = make_float2(x0.x + x2.x, x0.y + x2.y);
            float  ar = x0.x - x2.x, ai = x0.y - x2.y;
            float2 u1 = make_float2(ar * w.x - ai * w.y, ar * w.y + ai * w.x);
            float2 u2 = make_float2(x1.x + x3.x, x1.y + x3.y);
            float  br = x1.x - x3.x, bi = x1.y - x3.y;
            float2 u3 = make_float2(-br * w.y - bi * w.x, br * w.x - bi * w.y);
            const int base = tid + 3 * G;
            dst[pidx(base)]          = make_float2(u0.x + u2.x, u0.y + u2.y);
            dst[pidx(base + s4)]     = make_float2(u1.x + u3.x, u1.y + u3.y);
            float dr = u0.x - u2.x, di = u0.y - u2.y;
            dst[pidx(base + 2 * s4)] = make_float2(dr * w2.x - di * w2.y, dr * w2.y + di * w2.x);
            float er = u1.x - u3.x, ei = u1.y - u3.y;
            dst[pidx(base + 3 * s4)] = make_float2(er * w2.x - ei * w2.y, er * w2.y + ei * w2.x);
            __syncthreads();
        }
        // data now in W2

        // ---- P5: s4 (w=1) + fftshift + window -> register OLA; flush ----
        {
            float2 x0 = W2[pidx(tid)];
            float2 x1 = W2[pidx(tid + 256)];
            float2 x2 = W2[pidx(tid + 512)];
            float2 x3 = W2[pidx(tid + 768)];
            float2 u0 = make_float2(x0.x + x2.x, x0.y + x2.y);
            float2 u1 = make_float2(x0.x - x2.x, x0.y - x2.y);
            float2 u2 = make_float2(x1.x + x3.x, x1.y + x3.y);
            float2 u3 = make_float2(-(x1.y - x3.y), x1.x - x3.x);   // i*(x1-x3)
            float2 y;
            // n=tid+512 -> t2=tid     -> chunk fi   (acc0), window r0
            y = make_float2(u0.x - u2.x, u0.y - u2.y);
            acc0.x += y.x * r0.x;  acc0.y += y.y * r0.y;
            // n=tid+768 -> t2=tid+256 -> chunk fi+1 (acc1), window r1
            y = make_float2(u1.x - u3.x, u1.y - u3.y);
            acc1.x += y.x * r1.x;  acc1.y += y.y * r1.y;
            // n=tid     -> t2=tid+512 -> chunk fi+2 (acc2), window r2
            y = make_float2(u0.x + u2.x, u0.y + u2.y);
            acc2.x += y.x * r2.x;  acc2.y += y.y * r2.y;
            // n=tid+256 -> t2=tid+768 -> chunk fi+3 (acc3), window r3
            y = make_float2(u1.x + u3.x, u1.y + u3.y);
            acc3.x += y.x * r3.x;  acc3.y += y.y * r3.y;

            // flush chunk fi (complete)
            float2 v = acc0;
            long p = (long)(frame0 + fi) * HOP + 2 * tid - 1536;
            if (fi >= 3) {                           // interior: plain store
                if (p >= 0 && p < out_size)         out[p]     = v.x;
                if (p + 1 >= 0 && p + 1 < out_size) out[p + 1] = v.y;
            } else {                                 // seam: atomic
                if (p >= 0 && p < out_size)         atomicAdd(out + p,     v.x);
                if (p + 1 >= 0 && p + 1 < out_size) atomicAdd(out + p + 1, v.y);
            }
            // rotate accumulators
            acc0 = acc1; acc1 = acc2; acc2 = acc3;
            acc3 = make_float2(0.0f, 0.0f);
        }
        // no barrier: next write to W-buffers is behind P1's barrier
    }

    // ---- tail: chunks FPB..FPB+2 partial -> atomic ----
    #pragma unroll
    for (int e = 0; e < 3; ++e) {
        float2 v = (e == 0) ? acc0 : (e == 1) ? acc1 : acc2;
        long p = (long)(frame0 + FPB + e) * HOP + 2 * tid - 1536;
        if (p >= 0 && p < out_size)         atomicAdd(out + p,     v.x);
        if (p + 1 >= 0 && p + 1 < out_size) atomicAdd(out + p + 1, v.y);
    }
}

extern "C" void kernel_launch(void* const* d_in, const int* in_sizes, int n_in,
                              void* d_out, int out_size, void* d_ws, size_t ws_size,
                              hipStream_t stream) {
    const float* mag = (const float*)d_in[0];
    const float* ph  = (const float*)d_in[1];
    float* out = (float*)d_out;

    hipMemsetAsync(d_out, 0, (size_t)out_size * sizeof(float), stream);
    istft_kernel<<<NFRAMES / FPB, 256, 0, stream>>>(mag, ph, out, out_size);
}

// Round 14
// 71.194 us; speedup vs baseline: 2.9326x; 2.5406x over previous
//
#include <hip/hip_runtime.h>

#define WIN      2048
#define HOP      512
#define NFRAMES  16384
#define NBINS    1025      // WIN/2 + 1
#define FPB      8         // frames (= output chunks) per block

__device__ __forceinline__ int pidx(int a) { return a + (a >> 3); }
__device__ __forceinline__ float2 cmul(float2 a, float2 b) {
    return make_float2(a.x * b.x - a.y * b.y, a.x * b.y + a.y * b.x);
}
__device__ __forceinline__ float2 shfl63(float2 v) {    // lane l <-> 63-l
    return make_float2(__shfl_xor(v.x, 63, 64), __shfl_xor(v.y, 63, 64));
}

// ---------------------------------------------------------------------------
// 256 threads, 8 frames, software pipeline, NO spectrum LDS buffer:
// thread->bin map puts Hermitian mirror partners in the same wave at lane^63:
//   lane l<32: b = 32w+l ; l>=32: b = 193-32w+l ; (tid==63 -> b=128)
// so X[1024-k] arrives via __shfl_xor(.,63). Fixed points b=0 (DC, needs
// X[1024]) and b=128 (self-mirror) override from own registers.
// Per frame (4 barriers):
//  P1: convert staged loads -> X (4 bins, k=256m+b); mirrors via shuffle;
//      issue frame fi+1 loads; Hermitian half-size pack (tp = wpb*e^{i pi m/4})
//      fused with radix-4 stage0 (butterfly c=b) -> W1       [barrier]
//  P2-P4: stages s1..s3, tid-based, W1<->W2                  [3 barriers]
//  P5: s4 (twiddle=1) + fftshift + window -> acc0..3 register OLA;
//      flush chunk fi (plain interior / atomic seams); rotate acc.
// LDS = W1+W2 = 18432 B.
// launch_bounds(256,4): VGPR cap 128. HW occupancy steps at VGPR={64,128,256}
// (8/4/2 waves/SIMD) -> (256,6)/(256,8) both force the 64-cap and SPILLED
// (R12: 503 MB, R13: 325+220 MB scratch traffic). R10/R11 prove this family
// compiles to 64 VGPR at (256,4) -> if this body lands at 64, runtime gives
// 8 waves/SIMD for free.
// ---------------------------------------------------------------------------
__global__ __launch_bounds__(256, 4) void istft_kernel(
        const float* __restrict__ mag, const float* __restrict__ ph,
        float* __restrict__ out, int out_size) {
    __shared__ float2 W1[1152];          // 9216 B (pidx-padded 1024)
    __shared__ float2 W2[1152];          // 9216 B

    const int tid    = threadIdx.x;
    const int frame0 = blockIdx.x * FPB;
    const int l  = tid & 63;
    const int wv = tid >> 6;
    int bm = (l < 32) ? (32 * wv + l) : (193 - 32 * wv + l);
    if (tid == 63) bm = 128;             // formula would give 256
    const int b = bm;                    // spectrum base: bins k = 256m + b

    // ---- frame-invariant per-thread constants ----
    float2 wpb;                                    // e^{i pi b/1024}
    sincospif((float)b * (1.0f / 1024.0f), &wpb.y, &wpb.x);
    const float2 w0 = cmul(wpb, wpb);              // stage0 twiddle e^{2pi i b/1024}
    float2 wst1, wst2, wst3;                       // stage twiddles (tid-based)
    sincospif((float)(tid & ~3)  * (1.0f / 512.0f), &wst1.y, &wst1.x);
    sincospif((float)(tid & ~15) * (1.0f / 512.0f), &wst2.y, &wst2.x);
    sincospif((float)(tid & ~63) * (1.0f / 512.0f), &wst3.y, &wst3.x);

    // synthesis window (matches _gl_alg(2048,512,4094) folded with 1/1024)
    float2 rq[4];
    {
        const float inv2047 = 1.0f / 2047.0f;
        const float scale   = rsqrtf(4094.0f);
        float he[4], ho[4];
        float envE = 0.0f, envO = 0.0f;
        #pragma unroll
        for (int w = 0; w < 4; ++w) {
            he[w] = (0.54f - 0.46f * cospif((float)(2 * tid     + 512 * w) * 2.0f * inv2047)) * scale;
            ho[w] = (0.54f - 0.46f * cospif((float)(2 * tid + 1 + 512 * w) * 2.0f * inv2047)) * scale;
            envE += he[w] * he[w];
            envO += ho[w] * ho[w];
        }
        const float se = 1.0f / (envE * 1024.0f);
        const float so = 1.0f / (envO * 1024.0f);
        #pragma unroll
        for (int w = 0; w < 4; ++w) rq[w] = make_float2(he[w] * se, ho[w] * so);
    }
    const float2 r0 = rq[0], r1 = rq[1], r2 = rq[2], r3 = rq[3];
    const float RT = 0.70710678118654752f;         // sqrt(2)/2

    float  mgn[4], ppn[4], nymg, nyph;   // staged loads (current frame at P1)
    float2 acc0, acc1, acc2, acc3;       // live OLA chunks fi..fi+3 @ 2*tid
    acc0 = acc1 = acc2 = acc3 = make_float2(0.0f, 0.0f);

    // ---- prologue: stage frame 0 loads ----
    {
        const float* magf = mag + (size_t)frame0 * NBINS;
        const float* phf  = ph  + (size_t)frame0 * NBINS;
        #pragma unroll
        for (int m = 0; m < 4; ++m) {
            mgn[m] = magf[256 * m + b];
            ppn[m] = phf[256 * m + b];
        }
        nymg = magf[1024]; nyph = phf[1024];
    }

    for (int fi = 0; fi < FPB; ++fi) {
        // ---- P1: convert, shuffle mirrors, issue next loads, pack+s0 ----
        float2 X0, X1, X2, X3, Xn;
        {
            float s, c;
            __sincosf(ppn[0], &s, &c); X0 = make_float2(mgn[0] * c, mgn[0] * s);
            __sincosf(ppn[1], &s, &c); X1 = make_float2(mgn[1] * c, mgn[1] * s);
            __sincosf(ppn[2], &s, &c); X2 = make_float2(mgn[2] * c, mgn[2] * s);
            __sincosf(ppn[3], &s, &c); X3 = make_float2(mgn[3] * c, mgn[3] * s);
            __sincosf(nyph,   &s, &c); Xn = make_float2(nymg * c, 0.0f);
        }
        if (b == 0) X0.y = 0.0f;                   // DC imag dropped
        // mirrors: X[1024-(256m+b)] = partner's X[3-m], partner lane = l^63
        float2 Xm0 = shfl63(X3), Xm1 = shfl63(X2), Xm2 = shfl63(X1), Xm3 = shfl63(X0);
        if (b == 0)   { Xm0 = Xn; Xm1 = X3; Xm2 = X2; Xm3 = X1; }   // tid 0
        if (b == 128) { Xm0 = X3; Xm1 = X2; Xm2 = X1; Xm3 = X0; }   // tid 63

        if (fi < FPB - 1) {                        // issue next-frame loads
            const float* magf = mag + (size_t)(frame0 + fi + 1) * NBINS;
            const float* phf  = ph  + (size_t)(frame0 + fi + 1) * NBINS;
            #pragma unroll
            for (int m = 0; m < 4; ++m) {
                mgn[m] = magf[256 * m + b];
                ppn[m] = phf[256 * m + b];
            }
            nymg = magf[1024]; nyph = phf[1024];
        }

        // pack Zf[256m+b] = E + O', tp = wpb * e^{i pi m/4}; then stage0 (c=b)
        {
            float2 z[4];
            #pragma unroll
            for (int m = 0; m < 4; ++m) {
                float2 Xk = (m == 0) ? X0 : (m == 1) ? X1 : (m == 2) ? X2 : X3;
                float2 Xm = (m == 0) ? Xm0 : (m == 1) ? Xm1 : (m == 2) ? Xm2 : Xm3;
                float2 tp;
                if      (m == 0) tp = wpb;
                else if (m == 1) tp = make_float2(RT * (wpb.x - wpb.y), RT * (wpb.x + wpb.y));
                else if (m == 2) tp = make_float2(-wpb.y, wpb.x);
                else             tp = make_float2(-RT * (wpb.x + wpb.y), RT * (wpb.x - wpb.y));
                float Er = 0.5f * (Xk.x + Xm.x), Ei = 0.5f * (Xk.y - Xm.y);
                float Tr = Xm.x - Xk.x,          Ti = -(Xm.y + Xk.y);
                float Or = 0.5f * (tp.x * Ti + tp.y * Tr);
                float Oi = 0.5f * (tp.y * Ti - tp.x * Tr);
                z[m] = make_float2(Er + Or, Ei + Oi);
            }
            const float2 w = w0, w2 = cmul(w0, w0);
            float2 u0 = make_float2(z[0].x + z[2].x, z[0].y + z[2].y);
            float  ar = z[0].x - z[2].x, ai = z[0].y - z[2].y;
            float2 u1 = make_float2(ar * w.x - ai * w.y, ar * w.y + ai * w.x);
            float2 u2 = make_float2(z[1].x + z[3].x, z[1].y + z[3].y);
            float  br = z[1].x - z[3].x, bi = z[1].y - z[3].y;
            float2 u3 = make_float2(-br * w.y - bi * w.x, br * w.x - bi * w.y);
            const int base = 4 * b;                // butterfly c=b, s4=1
            W1[pidx(base)]     = make_float2(u0.x + u2.x, u0.y + u2.y);
            W1[pidx(base + 1)] = make_float2(u1.x + u3.x, u1.y + u3.y);
            float dr = u0.x - u2.x, di = u0.y - u2.y;
            W1[pidx(base + 2)] = make_float2(dr * w2.x - di * w2.y, dr * w2.y + di * w2.x);
            float er = u1.x - u3.x, ei = u1.y - u3.y;
            W1[pidx(base + 3)] = make_float2(er * w2.x - ei * w2.y, er * w2.y + ei * w2.x);
        }
        __syncthreads();

        // ---- P2/P3/P4: stages 1..3 (tid-based) ----
        #pragma unroll
        for (int st = 1; st < 4; ++st) {
            float2* src = (st == 2) ? W2 : W1;     // s1:W1->W2 s2:W2->W1 s3:W1->W2
            float2* dst = (st == 2) ? W1 : W2;
            const int s4 = 1 << (2 * st);
            const int G  = tid & ~(s4 - 1);
            const float2 w = (st == 1) ? wst1 : (st == 2) ? wst2 : wst3;
            const float2 w2 = cmul(w, w);
            float2 x0 = src[pidx(tid)];
            float2 x1 = src[pidx(tid + 256)];
            float2 x2 = src[pidx(tid + 512)];
            float2 x3 = src[pidx(tid + 768)];
            float2 u0 = make_float2(x0.x + x2.x, x0.y + x2.y);
            float  ar = x0.x - x2.x, ai = x0.y - x2.y;
            float2 u1 = make_float2(ar * w.x - ai * w.y, ar * w.y + ai * w.x);
            float2 u2 = make_float2(x1.x + x3.x, x1.y + x3.y);
            float  br = x1.x - x3.x, bi = x1.y - x3.y;
            float2 u3 = make_float2(-br * w.y - bi * w.x, br * w.x - bi * w.y);
            const int base = tid + 3 * G;
            dst[pidx(base)]          = make_float2(u0.x + u2.x, u0.y + u2.y);
            dst[pidx(base + s4)]     = make_float2(u1.x + u3.x, u1.y + u3.y);
            float dr = u0.x - u2.x, di = u0.y - u2.y;
            dst[pidx(base + 2 * s4)] = make_float2(dr * w2.x - di * w2.y, dr * w2.y + di * w2.x);
            float er = u1.x - u3.x, ei = u1.y - u3.y;
            dst[pidx(base + 3 * s4)] = make_float2(er * w2.x - ei * w2.y, er * w2.y + ei * w2.x);
            __syncthreads();
        }
        // data now in W2

        // ---- P5: s4 (w=1) + fftshift + window -> register OLA; flush ----
        {
            float2 x0 = W2[pidx(tid)];
            float2 x1 = W2[pidx(tid + 256)];
            float2 x2 = W2[pidx(tid + 512)];
            float2 x3 = W2[pidx(tid + 768)];
            float2 u0 = make_float2(x0.x + x2.x, x0.y + x2.y);
            float2 u1 = make_float2(x0.x - x2.x, x0.y - x2.y);
            float2 u2 = make_float2(x1.x + x3.x, x1.y + x3.y);
            float2 u3 = make_float2(-(x1.y - x3.y), x1.x - x3.x);   // i*(x1-x3)
            float2 y;
            // n=tid+512 -> t2=tid     -> chunk fi   (acc0), window r0
            y = make_float2(u0.x - u2.x, u0.y - u2.y);
            acc0.x += y.x * r0.x;  acc0.y += y.y * r0.y;
            // n=tid+768 -> t2=tid+256 -> chunk fi+1 (acc1), window r1
            y = make_float2(u1.x - u3.x, u1.y - u3.y);
            acc1.x += y.x * r1.x;  acc1.y += y.y * r1.y;
            // n=tid     -> t2=tid+512 -> chunk fi+2 (acc2), window r2
            y = make_float2(u0.x + u2.x, u0.y + u2.y);
            acc2.x += y.x * r2.x;  acc2.y += y.y * r2.y;
            // n=tid+256 -> t2=tid+768 -> chunk fi+3 (acc3), window r3
            y = make_float2(u1.x + u3.x, u1.y + u3.y);
            acc3.x += y.x * r3.x;  acc3.y += y.y * r3.y;

            // flush chunk fi (complete)
            float2 v = acc0;
            long p = (long)(frame0 + fi) * HOP + 2 * tid - 1536;
            if (fi >= 3) {                           // interior: plain store
                if (p >= 0 && p < out_size)         out[p]     = v.x;
                if (p + 1 >= 0 && p + 1 < out_size) out[p + 1] = v.y;
            } else {                                 // seam: atomic
                if (p >= 0 && p < out_size)         atomicAdd(out + p,     v.x);
                if (p + 1 >= 0 && p + 1 < out_size) atomicAdd(out + p + 1, v.y);
            }
            // rotate accumulators
            acc0 = acc1; acc1 = acc2; acc2 = acc3;
            acc3 = make_float2(0.0f, 0.0f);
        }
        // no barrier: next write to W-buffers is behind P1's barrier
    }

    // ---- tail: chunks FPB..FPB+2 partial -> atomic ----
    #pragma unroll
    for (int e = 0; e < 3; ++e) {
        float2 v = (e == 0) ? acc0 : (e == 1) ? acc1 : acc2;
        long p = (long)(frame0 + FPB + e) * HOP + 2 * tid - 1536;
        if (p >= 0 && p < out_size)         atomicAdd(out + p,     v.x);
        if (p + 1 >= 0 && p + 1 < out_size) atomicAdd(out + p + 1, v.y);
    }
}

extern "C" void kernel_launch(void* const* d_in, const int* in_sizes, int n_in,
                              void* d_out, int out_size, void* d_ws, size_t ws_size,
                              hipStream_t stream) {
    const float* mag = (const float*)d_in[0];
    const float* ph  = (const float*)d_in[1];
    float* out = (float*)d_out;

    hipMemsetAsync(d_out, 0, (size_t)out_size * sizeof(float), stream);
    istft_kernel<<<NFRAMES / FPB, 256, 0, stream>>>(mag, ph, out, out_size);
}

// Round 15
// 54.888 us; speedup vs baseline: 3.8038x; 1.2971x over previous
//
#include <hip/hip_runtime.h>

#define WIN      2048
#define HOP      512
#define NFRAMES  16384
#define NBINS    1025      // WIN/2 + 1
#define FPB      16        // frames (= output chunks) per block

__device__ __forceinline__ int pidx(int a) { return a + (a >> 3); }
__device__ __forceinline__ float2 cmul(float2 a, float2 b) {
    return make_float2(a.x * b.x - a.y * b.y, a.x * b.y + a.y * b.x);
}

// ---------------------------------------------------------------------------
// Zero ONLY the atomically-accumulated seam regions (global chunks g with
// g%16 in {0,1,2}; 3/16 of the output ~ 6.3 MB) instead of the full 33.5 MB.
// All other positions are covered exactly once by plain stores.
// ---------------------------------------------------------------------------
__global__ void zero_seams_kernel(float* __restrict__ out, int out_size) {
    const int i = blockIdx.x * blockDim.x + threadIdx.x; // seam float idx
    const int chunkSlot = i >> 9;                        // 512 floats/chunk
    const int off = i & 511;
    if (chunkSlot >= 3 * (NFRAMES / FPB + 1)) return;    // 3075 seam chunks
    const long g = (long)(chunkSlot / 3) * FPB + (chunkSlot % 3);
    const long p = g * HOP + off - 1536;
    if (p >= 0 && p < out_size) out[p] = 0.0f;
}

// ---------------------------------------------------------------------------
// 256 threads, 16 frames, software pipeline (4 barriers/frame):
//  P1: issue frame fi+1 global loads (regs); pack fi (Xk from regs, mirror
//      from Scur) fused with radix-4 stage0 -> W1             [barrier]
//  P2: s1  W1 -> W2                                           [barrier]
//  P3: s2  W2 -> W1                                           [barrier]
//  P4: s3  W1 -> W2 ; sincos(fi+1) -> xkB regs + Snxt         [barrier]
//  P5: s4 (twiddle=1) + fftshift + window -> acc0..acc3 register OLA
//      (thread owns intra-chunk offset 2*tid); flush chunk fi (acc0) to
//      global (plain interior / atomic seams); rotate acc, copy xkB->xkA,
//      swap Scur/Snxt. No barrier (next W-buffer write is 2 barriers away).
// Synthesis window rs computed in-kernel; no init kernel, d_ws unused.
// ---------------------------------------------------------------------------
__global__ __launch_bounds__(256, 4) void istft_kernel(
        const float* __restrict__ mag, const float* __restrict__ ph,
        float* __restrict__ out, int out_size) {
    __shared__ float2 W1[1152];          // 9216 B (pidx-padded 1024)
    __shared__ float2 W2[1152];          // 9216 B
    __shared__ float2 S0[1026], S1[1026];// 2 x 8208 B spectrum buffers

    const int tid    = threadIdx.x;
    const int frame0 = blockIdx.x * FPB;

    // ---- frame-invariant per-thread constants ----
    float2 wpk;                                    // e^{2pi i tid/2048}
    sincospif((float)tid * (1.0f / 1024.0f), &wpk.y, &wpk.x);
    float2 wst[4], w2st[4];
    wst[0] = cmul(wpk, wpk);                       // e^{2pi i tid/1024}
    sincospif((float)(tid & ~3)  * (1.0f / 512.0f), &wst[1].y, &wst[1].x);
    sincospif((float)(tid & ~15) * (1.0f / 512.0f), &wst[2].y, &wst[2].x);
    sincospif((float)(tid & ~63) * (1.0f / 512.0f), &wst[3].y, &wst[3].x);
    #pragma unroll
    for (int q = 0; q < 4; ++q) w2st[q] = cmul(wst[q], wst[q]);

    // synthesis window (matches _gl_alg(2048,512,4094) folded with 1/1024):
    // rq[w] = {rs[2*tid+512w], rs[2*tid+1+512w]}
    float2 rq[4];
    {
        const float inv2047 = 1.0f / 2047.0f;
        const float scale   = rsqrtf(4094.0f);
        float he[4], ho[4];
        float envE = 0.0f, envO = 0.0f;
        #pragma unroll
        for (int w = 0; w < 4; ++w) {
            he[w] = (0.54f - 0.46f * cospif((float)(2 * tid     + 512 * w) * 2.0f * inv2047)) * scale;
            ho[w] = (0.54f - 0.46f * cospif((float)(2 * tid + 1 + 512 * w) * 2.0f * inv2047)) * scale;
            envE += he[w] * he[w];
            envO += ho[w] * ho[w];
        }
        const float se = 1.0f / (envE * 1024.0f);
        const float so = 1.0f / (envO * 1024.0f);
        #pragma unroll
        for (int w = 0; w < 4; ++w) rq[w] = make_float2(he[w] * se, ho[w] * so);
    }
    const float2 r0 = rq[0], r1 = rq[1], r2 = rq[2], r3 = rq[3];
    const float RT = 0.70710678118654752f;         // sqrt(2)/2

    float2 xkA0, xkA1, xkA2, xkA3;       // forward bins, current frame
    float2 xkB0, xkB1, xkB2, xkB3;       // forward bins, next frame
    float  mgn[4], ppn[4], nymg, nyph;   // staged loads for next frame
    float2 acc0, acc1, acc2, acc3;       // live OLA chunks fi..fi+3 @ 2*tid
    acc0 = acc1 = acc2 = acc3 = make_float2(0.0f, 0.0f);
    float2* Scur = S0;
    float2* Snxt = S1;

    // ---- prologue: load + convert frame 0, write Scur ----
    {
        const float* magf = mag + (size_t)frame0 * NBINS;
        const float* phf  = ph  + (size_t)frame0 * NBINS;
        #pragma unroll
        for (int j = 0; j < 4; ++j) {
            mgn[j] = magf[tid + 256 * j];
            ppn[j] = phf[tid + 256 * j];
        }
        nymg = magf[1024]; nyph = phf[1024];
        float2 X[4];
        #pragma unroll
        for (int j = 0; j < 4; ++j) {
            float s, c;
            __sincosf(ppn[j], &s, &c);
            X[j] = make_float2(mgn[j] * c, mgn[j] * s);
            if (j == 0 && tid == 0) X[j].y = 0.0f;     // DC imag
            Scur[tid + 256 * j] = X[j];
        }
        xkA0 = X[0]; xkA1 = X[1]; xkA2 = X[2]; xkA3 = X[3];
        if (tid == 0) {
            float s, c;
            __sincosf(nyph, &s, &c);
            Scur[1024] = make_float2(nymg * c, 0.0f);  // Nyquist imag = 0
        }
    }
    __syncthreads();

    for (int fi = 0; fi < FPB; ++fi) {
        // ---- P1: issue next-frame loads, then pack + s0 -> W1 ----
        if (fi < FPB - 1) {
            const float* magf = mag + (size_t)(frame0 + fi + 1) * NBINS;
            const float* phf  = ph  + (size_t)(frame0 + fi + 1) * NBINS;
            #pragma unroll
            for (int j = 0; j < 4; ++j) {
                mgn[j] = magf[tid + 256 * j];
                ppn[j] = phf[tid + 256 * j];
            }
            nymg = magf[1024]; nyph = phf[1024];
        }
        {
            float2 z[4];
            #pragma unroll
            for (int j = 0; j < 4; ++j) {
                float2 Xk = (j == 0) ? xkA0 : (j == 1) ? xkA1 : (j == 2) ? xkA2 : xkA3;
                float2 Xm = Scur[1024 - (tid + 256 * j)];
                float2 wj;                         // wpk * e^{i pi j/4}
                if      (j == 0) wj = wpk;
                else if (j == 1) wj = make_float2(RT * (wpk.x - wpk.y), RT * (wpk.x + wpk.y));
                else if (j == 2) wj = make_float2(-wpk.y, wpk.x);
                else             wj = make_float2(-RT * (wpk.x + wpk.y), RT * (wpk.x - wpk.y));
                float Er = 0.5f * (Xk.x + Xm.x), Ei = 0.5f * (Xk.y - Xm.y);
                float Tr = Xm.x - Xk.x,          Ti = -Xm.y - Xk.y;
                float Or = 0.5f * (wj.x * Ti + wj.y * Tr);
                float Oi = 0.5f * (wj.y * Ti - wj.x * Tr);
                z[j] = make_float2(Er + Or, Ei + Oi);
            }
            float2 w = wst[0], w2 = w2st[0];
            float2 u0 = make_float2(z[0].x + z[2].x, z[0].y + z[2].y);
            float  ar = z[0].x - z[2].x, ai = z[0].y - z[2].y;
            float2 u1 = make_float2(ar * w.x - ai * w.y, ar * w.y + ai * w.x);
            float2 u2 = make_float2(z[1].x + z[3].x, z[1].y + z[3].y);
            float  br = z[1].x - z[3].x, bi = z[1].y - z[3].y;
            float2 u3 = make_float2(-br * w.y - bi * w.x, br * w.x - bi * w.y);
            const int base = 4 * tid;              // tid + 3*G, G=tid, s4=1
            W1[pidx(base)]     = make_float2(u0.x + u2.x, u0.y + u2.y);
            W1[pidx(base + 1)] = make_float2(u1.x + u3.x, u1.y + u3.y);
            float dr = u0.x - u2.x, di = u0.y - u2.y;
            W1[pidx(base + 2)] = make_float2(dr * w2.x - di * w2.y, dr * w2.y + di * w2.x);
            float er = u1.x - u3.x, ei = u1.y - u3.y;
            W1[pidx(base + 3)] = make_float2(er * w2.x - ei * w2.y, er * w2.y + ei * w2.x);
        }
        __syncthreads();

        // ---- P2/P3/P4: stages 1..3 ----
        #pragma unroll
        for (int st = 1; st < 4; ++st) {
            float2* src = (st == 2) ? W2 : W1;     // s1:W1->W2 s2:W2->W1 s3:W1->W2
            float2* dst = (st == 2) ? W1 : W2;
            const int s4 = 1 << (2 * st);
            const int G  = tid & ~(s4 - 1);
            const float2 w = wst[st], w2 = w2st[st];
            float2 x0 = src[pidx(tid)];
            float2 x1 = src[pidx(tid + 256)];
            float2 x2 = src[pidx(tid + 512)];
            float2 x3 = src[pidx(tid + 768)];
            float2 u0 = make_float2(x0.x + x2.x, x0.y + x2.y);
            float  ar = x0.x - x2.x, ai = x0.y - x2.y;
            float2 u1 = make_float2(ar * w.x - ai * w.y, ar * w.y + ai * w.x);
            float2 u2 = make_float2(x1.x + x3.x, x1.y + x3.y);
            float  br = x1.x - x3.x, bi = x1.y - x3.y;
            float2 u3 = make_float2(-br * w.y - bi * w.x, br * w.x - bi * w.y);
            const int base = tid + 3 * G;
            dst[pidx(base)]          = make_float2(u0.x + u2.x, u0.y + u2.y);
            dst[pidx(base + s4)]     = make_float2(u1.x + u3.x, u1.y + u3.y);
            float dr = u0.x - u2.x, di = u0.y - u2.y;
            dst[pidx(base + 2 * s4)] = make_float2(dr * w2.x - di * w2.y, dr * w2.y + di * w2.x);
            float er = u1.x - u3.x, ei = u1.y - u3.y;
            dst[pidx(base + 3 * s4)] = make_float2(er * w2.x - ei * w2.y, er * w2.y + ei * w2.x);

            // fold next-frame spectrum conversion into the s3 phase
            if (st == 3 && fi < FPB - 1) {
                float2 X[4];
                #pragma unroll
                for (int j = 0; j < 4; ++j) {
                    float s, c;
                    __sincosf(ppn[j], &s, &c);
                    X[j] = make_float2(mgn[j] * c, mgn[j] * s);
                    if (j == 0 && tid == 0) X[j].y = 0.0f;
                    Snxt[tid + 256 * j] = X[j];
                }
                xkB0 = X[0]; xkB1 = X[1]; xkB2 = X[2]; xkB3 = X[3];
                if (tid == 0) {
                    float s, c;
                    __sincosf(nyph, &s, &c);
                    Snxt[1024] = make_float2(nymg * c, 0.0f);
                }
            }
            __syncthreads();
        }
        // data now in W2

        // ---- P5: s4 (w=1) + fftshift + window -> register OLA; flush ----
        {
            float2 x0 = W2[pidx(tid)];
            float2 x1 = W2[pidx(tid + 256)];
            float2 x2 = W2[pidx(tid + 512)];
            float2 x3 = W2[pidx(tid + 768)];
            float2 u0 = make_float2(x0.x + x2.x, x0.y + x2.y);
            float2 u1 = make_float2(x0.x - x2.x, x0.y - x2.y);
            float2 u2 = make_float2(x1.x + x3.x, x1.y + x3.y);
            float2 u3 = make_float2(-(x1.y - x3.y), x1.x - x3.x);   // i*(x1-x3)
            float2 y;
            // n=tid+512 -> t2=tid     -> chunk fi   (acc0), window r0
            y = make_float2(u0.x - u2.x, u0.y - u2.y);
            acc0.x += y.x * r0.x;  acc0.y += y.y * r0.y;
            // n=tid+768 -> t2=tid+256 -> chunk fi+1 (acc1), window r1
            y = make_float2(u1.x - u3.x, u1.y - u3.y);
            acc1.x += y.x * r1.x;  acc1.y += y.y * r1.y;
            // n=tid     -> t2=tid+512 -> chunk fi+2 (acc2), window r2
            y = make_float2(u0.x + u2.x, u0.y + u2.y);
            acc2.x += y.x * r2.x;  acc2.y += y.y * r2.y;
            // n=tid+256 -> t2=tid+768 -> chunk fi+3 (acc3), window r3
            y = make_float2(u1.x + u3.x, u1.y + u3.y);
            acc3.x += y.x * r3.x;  acc3.y += y.y * r3.y;

            // flush chunk fi (complete)
            float2 v = acc0;
            long p = (long)(frame0 + fi) * HOP + 2 * tid - 1536;
            if (fi >= 3) {                           // interior: plain store
                if (p >= 0 && p < out_size)         out[p]     = v.x;
                if (p + 1 >= 0 && p + 1 < out_size) out[p + 1] = v.y;
            } else {                                 // seam: atomic
                if (p >= 0 && p < out_size)         atomicAdd(out + p,     v.x);
                if (p + 1 >= 0 && p + 1 < out_size) atomicAdd(out + p + 1, v.y);
            }
            // rotate state for next slot
            acc0 = acc1; acc1 = acc2; acc2 = acc3;
            acc3 = make_float2(0.0f, 0.0f);
            xkA0 = xkB0; xkA1 = xkB1; xkA2 = xkB2; xkA3 = xkB3;
            float2* tmp = Scur; Scur = Snxt; Snxt = tmp;
        }
        // no barrier: next write to W-buffers is 2 barriers away
    }

    // ---- tail: chunks FPB..FPB+2 partial -> atomic ----
    #pragma unroll
    for (int e = 0; e < 3; ++e) {
        float2 v = (e == 0) ? acc0 : (e == 1) ? acc1 : acc2;
        long p = (long)(frame0 + FPB + e) * HOP + 2 * tid - 1536;
        if (p >= 0 && p < out_size)         atomicAdd(out + p,     v.x);
        if (p + 1 >= 0 && p + 1 < out_size) atomicAdd(out + p + 1, v.y);
    }
}

extern "C" void kernel_launch(void* const* d_in, const int* in_sizes, int n_in,
                              void* d_out, int out_size, void* d_ws, size_t ws_size,
                              hipStream_t stream) {
    const float* mag = (const float*)d_in[0];
    const float* ph  = (const float*)d_in[1];
    float* out = (float*)d_out;

    // zero only the atomic seam regions (~6.3 MB) instead of all 33.5 MB
    const int seamFloats = 3 * (NFRAMES / FPB + 1) * HOP;   // 1,574,400
    zero_seams_kernel<<<(seamFloats + 255) / 256, 256, 0, stream>>>(out, out_size);
    istft_kernel<<<NFRAMES / FPB, 256, 0, stream>>>(mag, ph, out, out_size);
}